// Round 1
// baseline (947.891 us; speedup 1.0000x reference)
//
#include <hip/hip_runtime.h>
#include <math.h>

#define N_LB  1024
#define N_ULB 7168
#define NTOT  8192
#define DD    128
#define CC    10

// float offsets into d_out
#define O_ANCHOR 0
#define O_POS    917504
#define O_LBF    1835008
#define O_LBOH   1966080
#define O_LLB    1976320
#define O_LULB1  1986560
#define O_LULB2  2058240
#define O_CN     2129920

#define BI 32
#define BJ 64
#define QJS 132   // padded row stride (floats) for qj tile

__device__ __forceinline__ const float* qrow(const float* lb, const float* an, int r) {
  return (r < N_LB) ? (lb + (size_t)r * DD) : (an + (size_t)(r - N_LB) * DD);
}

// -------- class_num: pseudo-label histogram + labeled counts ----------------
__global__ void classnum_kernel(const float* __restrict__ l1g, const float* __restrict__ l2g,
                                const int* __restrict__ y_lb, float* __restrict__ cn) {
  int t = blockIdx.x * blockDim.x + threadIdx.x;
  if (t < N_ULB) {
    float a[CC], b[CC];
    #pragma unroll
    for (int c = 0; c < CC; ++c) { a[c] = l1g[t * CC + c]; b[c] = l2g[t * CC + c]; }
    // mp = max softmax(logits/0.5) = 1/sum(exp(2l - 2lmax))
    float m1 = -INFINITY, m2 = -INFINITY;
    #pragma unroll
    for (int c = 0; c < CC; ++c) { m1 = fmaxf(m1, 2.f * a[c]); m2 = fmaxf(m2, 2.f * b[c]); }
    float Z1 = 0.f, Z2 = 0.f;
    #pragma unroll
    for (int c = 0; c < CC; ++c) { Z1 += expf(2.f * a[c] - m1); Z2 += expf(2.f * b[c] - m2); }
    bool gt = (1.0f / Z1) >= (1.0f / Z2);
    float g[CC];
    #pragma unroll
    for (int c = 0; c < CC; ++c) g[c] = gt ? a[c] : b[c];
    float mg = -INFINITY;
    #pragma unroll
    for (int c = 0; c < CC; ++c) mg = fmaxf(mg, g[c]);
    float p[CC]; float Zg = 0.f;
    #pragma unroll
    for (int c = 0; c < CC; ++c) { p[c] = expf(g[c] - mg); Zg += p[c]; }
    // masked logits, first-occurrence argmax
    float best = ((p[0] / Zg) >= 0.95f) ? g[0] : 0.0f;
    int bi = 0;
    #pragma unroll
    for (int c = 1; c < CC; ++c) {
      float v = ((p[c] / Zg) >= 0.95f) ? g[c] : 0.0f;
      if (v > best) { best = v; bi = c; }
    }
    if (best != 0.0f) atomicAdd(&cn[bi], 1.0f);
  } else if (t < NTOT) {
    atomicAdd(&cn[y_lb[t - N_ULB]], 1.0f);
  }
}

// -------- attention: online (max, argmax, sumexp) per row -------------------
__global__ __launch_bounds__(256) void attn_kernel(
    const float* __restrict__ lb_feat, const float* __restrict__ anchor,
    const float* __restrict__ lb_one_hot, const float* __restrict__ lulb1,
    float* __restrict__ out)
{
  __shared__ float qi[BI][DD];
  __shared__ float qj[BJ][QJS];
  const int tid = threadIdx.x;
  const int blk = blockIdx.x;
  const int ti = tid >> 5;   // 0..7 -> 4 rows each
  const int tj = tid & 31;   // cols {tj, tj+32} within tile
  const int i0 = ti * 4;

  // stage Q_I (32 x 128)
  #pragma unroll
  for (int t = tid; t < BI * (DD / 4); t += 256) {
    int row = t >> 5, c4 = t & 31;
    const float* p = qrow(lb_feat, anchor, blk * BI + row);
    *(float4*)&qi[row][c4 * 4] = *(const float4*)(p + c4 * 4);
  }

  float m[4], Z[4]; int jm[4];
  #pragma unroll
  for (int r = 0; r < 4; ++r) { m[r] = -INFINITY; Z[r] = 0.0f; jm[r] = 0; }

  for (int jt = 0; jt < NTOT / BJ; ++jt) {
    __syncthreads();
    #pragma unroll
    for (int t = tid; t < BJ * (DD / 4); t += 256) {
      int row = t >> 5, c4 = t & 31;
      const float* p = qrow(lb_feat, anchor, jt * BJ + row);
      *(float4*)&qj[row][c4 * 4] = *(const float4*)(p + c4 * 4);
    }
    __syncthreads();

    float acc[4][2] = {{0.f, 0.f}, {0.f, 0.f}, {0.f, 0.f}, {0.f, 0.f}};
    #pragma unroll 8
    for (int d = 0; d < DD; d += 4) {
      float4 b0 = *(const float4*)&qj[tj][d];
      float4 b1 = *(const float4*)&qj[tj + 32][d];
      #pragma unroll
      for (int r = 0; r < 4; ++r) {
        float4 a = *(const float4*)&qi[i0 + r][d];
        acc[r][0] = fmaf(a.w, b0.w, fmaf(a.z, b0.z, fmaf(a.y, b0.y, fmaf(a.x, b0.x, acc[r][0]))));
        acc[r][1] = fmaf(a.w, b1.w, fmaf(a.z, b1.z, fmaf(a.y, b1.y, fmaf(a.x, b1.x, acc[r][1]))));
      }
    }
    #pragma unroll
    for (int r = 0; r < 4; ++r) {
      #pragma unroll
      for (int c = 0; c < 2; ++c) {
        float s = acc[r][c] * 10.0f;       // / TAU
        int j = jt * BJ + tj + c * 32;
        if (s > m[r]) { Z[r] = Z[r] * __expf(m[r] - s) + 1.0f; m[r] = s; jm[r] = j; }
        else          { Z[r] += __expf(s - m[r]); }
      }
    }
  }

  // combine across the 32 lanes sharing the same row group
  #pragma unroll
  for (int r = 0; r < 4; ++r) {
    #pragma unroll
    for (int off = 16; off >= 1; off >>= 1) {
      float mo = __shfl_xor(m[r], off, 32);
      float Zo = __shfl_xor(Z[r], off, 32);
      int   jo = __shfl_xor(jm[r], off, 32);
      if (mo > m[r] || (mo == m[r] && jo < jm[r])) {
        Z[r] = Zo + Z[r] * __expf(m[r] - mo);
        m[r] = mo; jm[r] = jo;
      } else {
        Z[r] += Zo * __expf(mo - m[r]);
      }
    }
  }

  if (tj == 0) {
    #pragma unroll
    for (int r = 0; r < 4; ++r) {
      int gi = blk * BI + i0 + r;
      float av = 1.0f / Z[r];   // att value at the row max
      float* orow = (gi < N_LB) ? (out + O_LLB + (size_t)gi * CC)
                                : (out + O_LULB1 + (size_t)(gi - N_LB) * CC);
      if (av >= 0.6f) {
        int j = jm[r];
        if (j < N_LB) {
          #pragma unroll
          for (int c = 0; c < CC; ++c) orow[c] = av * lb_one_hot[j * CC + c];
        } else {
          const float* lg = lulb1 + (size_t)(j - N_LB) * CC;
          float mx = lg[0];
          #pragma unroll
          for (int c = 1; c < CC; ++c) mx = fmaxf(mx, lg[c]);
          float e[CC]; float sum = 0.f;
          #pragma unroll
          for (int c = 0; c < CC; ++c) { e[c] = expf(lg[c] - mx); sum += e[c]; }
          #pragma unroll
          for (int c = 0; c < CC; ++c) orow[c] = av * (e[c] / sum);
        }
      } else {
        #pragma unroll
        for (int c = 0; c < CC; ++c) orow[c] = 0.0f;
      }
    }
  }
}

extern "C" void kernel_launch(void* const* d_in, const int* in_sizes, int n_in,
                              void* d_out, int out_size, void* d_ws, size_t ws_size,
                              hipStream_t stream) {
  (void)in_sizes; (void)n_in; (void)d_ws; (void)ws_size; (void)out_size;
  const float* anchor   = (const float*)d_in[0];
  const float* positive = (const float*)d_in[1];
  const float* lb_feat  = (const float*)d_in[2];
  const float* lb_oh    = (const float*)d_in[3];
  const float* lulb1    = (const float*)d_in[5];
  const float* lulb2    = (const float*)d_in[6];
  const int*   y_lb     = (const int*)d_in[7];
  float* out = (float*)d_out;

  hipMemcpyAsync(out + O_ANCHOR, anchor,   (size_t)917504 * 4, hipMemcpyDeviceToDevice, stream);
  hipMemcpyAsync(out + O_POS,    positive, (size_t)917504 * 4, hipMemcpyDeviceToDevice, stream);
  hipMemcpyAsync(out + O_LBF,    lb_feat,  (size_t)131072 * 4, hipMemcpyDeviceToDevice, stream);
  hipMemcpyAsync(out + O_LBOH,   lb_oh,    (size_t)10240  * 4, hipMemcpyDeviceToDevice, stream);
  hipMemcpyAsync(out + O_LULB2,  lulb2,    (size_t)71680  * 4, hipMemcpyDeviceToDevice, stream);
  hipMemsetAsync(out + O_CN, 0, CC * sizeof(float), stream);

  classnum_kernel<<<(NTOT + 255) / 256, 256, 0, stream>>>(lulb1, lulb2, y_lb, out + O_CN);
  attn_kernel<<<NTOT / BI, 256, 0, stream>>>(lb_feat, anchor, lb_oh, lulb1, out);
}

// Round 2
// 129.386 us; speedup vs baseline: 7.3261x; 7.3261x over previous
//
#include <hip/hip_runtime.h>
#include <math.h>

#define N_LB  1024
#define N_ULB 7168
#define NTOT  8192
#define DD    128
#define CC    10

// float offsets into d_out
#define O_ANCHOR 0
#define O_POS    917504
#define O_LBF    1835008
#define O_LBOH   1966080
#define O_LLB    1976320
#define O_LULB1  1986560
#define O_LULB2  2058240
#define O_CN     2129920

typedef short bf16x8 __attribute__((ext_vector_type(8)));
typedef float f32x16 __attribute__((ext_vector_type(16)));

__device__ __forceinline__ ushort f2bf(float f) {
  union { float f; unsigned u; } a; a.f = f;
  unsigned r = a.u + 0x7FFFu + ((a.u >> 16) & 1u);   // RNE
  return (ushort)(r >> 16);
}

// -------- f32 -> bf16 convert (Q staging into workspace) --------------------
__global__ void f2bf_kernel(const float* __restrict__ in, ushort* __restrict__ out, int n4) {
  int t = blockIdx.x * blockDim.x + threadIdx.x;
  if (t < n4) {
    float4 v = ((const float4*)in)[t];
    ushort4 u;
    u.x = f2bf(v.x); u.y = f2bf(v.y); u.z = f2bf(v.z); u.w = f2bf(v.w);
    ((ushort4*)out)[t] = u;
  }
}

// -------- class_num: pseudo-label histogram + labeled counts ----------------
__global__ void classnum_kernel(const float* __restrict__ l1g, const float* __restrict__ l2g,
                                const int* __restrict__ y_lb, float* __restrict__ cn) {
  int t = blockIdx.x * blockDim.x + threadIdx.x;
  if (t < N_ULB) {
    float a[CC], b[CC];
    #pragma unroll
    for (int c = 0; c < CC; ++c) { a[c] = l1g[t * CC + c]; b[c] = l2g[t * CC + c]; }
    float m1 = -INFINITY, m2 = -INFINITY;
    #pragma unroll
    for (int c = 0; c < CC; ++c) { m1 = fmaxf(m1, 2.f * a[c]); m2 = fmaxf(m2, 2.f * b[c]); }
    float Z1 = 0.f, Z2 = 0.f;
    #pragma unroll
    for (int c = 0; c < CC; ++c) { Z1 += expf(2.f * a[c] - m1); Z2 += expf(2.f * b[c] - m2); }
    bool gt = (1.0f / Z1) >= (1.0f / Z2);
    float g[CC];
    #pragma unroll
    for (int c = 0; c < CC; ++c) g[c] = gt ? a[c] : b[c];
    float mg = -INFINITY;
    #pragma unroll
    for (int c = 0; c < CC; ++c) mg = fmaxf(mg, g[c]);
    float p[CC]; float Zg = 0.f;
    #pragma unroll
    for (int c = 0; c < CC; ++c) { p[c] = expf(g[c] - mg); Zg += p[c]; }
    float best = ((p[0] / Zg) >= 0.95f) ? g[0] : 0.0f;
    int bi = 0;
    #pragma unroll
    for (int c = 1; c < CC; ++c) {
      float v = ((p[c] / Zg) >= 0.95f) ? g[c] : 0.0f;
      if (v > best) { best = v; bi = c; }
    }
    if (best != 0.0f) atomicAdd(&cn[bi], 1.0f);
  } else if (t < NTOT) {
    atomicAdd(&cn[y_lb[t - N_ULB]], 1.0f);
  }
}

// -------- attention: MFMA QQ^T with online (max, argmax, sumexp) ------------
// 256 blocks x 512 threads (8 waves). Block owns 32 rows (A-frags in regs).
// Waves split the 8192 j's into 32-col tiles; per tile: 8x mfma_32x32x16_bf16
// (K=128), then branchless online-softmax update on the 16 acc regs.
__global__ __launch_bounds__(512) void attn_mfma(
    const ushort* __restrict__ Qb, const float* __restrict__ lb_one_hot,
    const float* __restrict__ lulb1, float* __restrict__ out)
{
  __shared__ float lm[8][32];
  __shared__ float lz[8][32];
  __shared__ int   lj[8][32];

  const int tid = threadIdx.x;
  const int w  = tid >> 6;
  const int l  = tid & 63;
  const int lr = l & 31;   // A-row / B-col within tile (C/D col = lane&31)
  const int kh = l >> 5;   // k-half select
  const int blk = blockIdx.x;

  // A fragments: rows blk*32 + lr, k = e*16 + kh*8 + [0..7]. Same pattern for B
  // (operand layouts mirror; shared K-permutation cancels in A.B^T).
  bf16x8 a[8];
  {
    const ushort* ap = Qb + (size_t)(blk * 32 + lr) * DD + kh * 8;
    #pragma unroll
    for (int e = 0; e < 8; ++e) a[e] = *(const bf16x8*)(ap + e * 16);
  }

  float m[16], Z[16]; int jm[16];
  #pragma unroll
  for (int e = 0; e < 16; ++e) { m[e] = -INFINITY; Z[e] = 0.0f; jm[e] = 0; }

  for (int t = 0; t < NTOT / 32 / 8; ++t) {     // 32 tiles per wave
    const int j0 = (w + t * 8) * 32;            // j increases with t (tie-break)
    const ushort* bp = Qb + (size_t)(j0 + lr) * DD + kh * 8;
    bf16x8 b[8];
    #pragma unroll
    for (int e = 0; e < 8; ++e) b[e] = *(const bf16x8*)(bp + e * 16);
    f32x16 c;
    #pragma unroll
    for (int e = 0; e < 16; ++e) c[e] = 0.0f;
    #pragma unroll
    for (int e = 0; e < 8; ++e)
      c = __builtin_amdgcn_mfma_f32_32x32x16_bf16(a[e], b[e], c, 0, 0, 0);

    const int j = j0 + lr;                      // this lane's column
    #pragma unroll
    for (int e = 0; e < 16; ++e) {
      float s  = c[e] * 10.0f;                  // / TAU
      float d  = s - m[e];
      float ex = __expf(-fabsf(d));             // exp(-|s-m|)
      bool  gt = d > 0.0f;
      jm[e] = gt ? j : jm[e];
      m[e]  = gt ? s : m[e];
      Z[e]  = fmaf(Z[e], gt ? ex : 1.0f, gt ? 1.0f : ex);
    }
  }

  // reduce across the 32 lanes of each half (cols) — rows stay fixed
  #pragma unroll
  for (int off = 1; off <= 16; off <<= 1) {
    #pragma unroll
    for (int e = 0; e < 16; ++e) {
      float mo = __shfl_xor(m[e], off);
      float Zo = __shfl_xor(Z[e], off);
      int   jo = __shfl_xor(jm[e], off);
      bool take = (mo > m[e]) || (mo == m[e] && jo < jm[e]);
      if (take) { Z[e] = Zo + Z[e] * __expf(m[e] - mo); m[e] = mo; jm[e] = jo; }
      else      { Z[e] = Z[e] + Zo * __expf(mo - m[e]); }
    }
  }

  if (lr == 0) {
    #pragma unroll
    for (int e = 0; e < 16; ++e) {
      int r = (e & 3) + 8 * (e >> 2) + 4 * kh;  // verified C/D row mapping
      lm[w][r] = m[e]; lz[w][r] = Z[e]; lj[w][r] = jm[e];
    }
  }
  __syncthreads();

  if (tid < 32) {
    float mf = -INFINITY, Zf = 0.0f; int jf = 0x7fffffff;
    #pragma unroll
    for (int wv = 0; wv < 8; ++wv) {
      float mo = lm[wv][tid], Zo = lz[wv][tid]; int jo = lj[wv][tid];
      bool take = (mo > mf) || (mo == mf && jo < jf);
      if (take) { Zf = Zo + Zf * expf(mf - mo); mf = mo; jf = jo; }
      else      { Zf = Zf + Zo * expf(mo - mf); }
    }
    int gi = blk * 32 + tid;
    float av = 1.0f / Zf;                       // att value at row max
    float* orow = (gi < N_LB) ? (out + O_LLB + (size_t)gi * CC)
                              : (out + O_LULB1 + (size_t)(gi - N_LB) * CC);
    if (av >= 0.6f) {
      if (jf < N_LB) {
        #pragma unroll
        for (int c = 0; c < CC; ++c) orow[c] = av * lb_one_hot[jf * CC + c];
      } else {
        const float* lg = lulb1 + (size_t)(jf - N_LB) * CC;
        float mx = lg[0];
        #pragma unroll
        for (int c = 1; c < CC; ++c) mx = fmaxf(mx, lg[c]);
        float e[CC]; float sum = 0.f;
        #pragma unroll
        for (int c = 0; c < CC; ++c) { e[c] = expf(lg[c] - mx); sum += e[c]; }
        #pragma unroll
        for (int c = 0; c < CC; ++c) orow[c] = av * (e[c] / sum);
      }
    } else {
      #pragma unroll
      for (int c = 0; c < CC; ++c) orow[c] = 0.0f;
    }
  }
}

extern "C" void kernel_launch(void* const* d_in, const int* in_sizes, int n_in,
                              void* d_out, int out_size, void* d_ws, size_t ws_size,
                              hipStream_t stream) {
  (void)in_sizes; (void)n_in; (void)ws_size; (void)out_size;
  const float* anchor   = (const float*)d_in[0];
  const float* positive = (const float*)d_in[1];
  const float* lb_feat  = (const float*)d_in[2];
  const float* lb_oh    = (const float*)d_in[3];
  const float* lulb1    = (const float*)d_in[5];
  const float* lulb2    = (const float*)d_in[6];
  const int*   y_lb     = (const int*)d_in[7];
  float* out = (float*)d_out;
  ushort* Qb = (ushort*)d_ws;   // 8192 x 128 bf16 = 2 MB

  hipMemcpyAsync(out + O_ANCHOR, anchor,   (size_t)917504 * 4, hipMemcpyDeviceToDevice, stream);
  hipMemcpyAsync(out + O_POS,    positive, (size_t)917504 * 4, hipMemcpyDeviceToDevice, stream);
  hipMemcpyAsync(out + O_LBF,    lb_feat,  (size_t)131072 * 4, hipMemcpyDeviceToDevice, stream);
  hipMemcpyAsync(out + O_LBOH,   lb_oh,    (size_t)10240  * 4, hipMemcpyDeviceToDevice, stream);
  hipMemcpyAsync(out + O_LULB2,  lulb2,    (size_t)71680  * 4, hipMemcpyDeviceToDevice, stream);
  hipMemsetAsync(out + O_CN, 0, CC * sizeof(float), stream);

  // stage Q = [lb_feat; anchor] as bf16 in workspace
  f2bf_kernel<<<(131072 / 4 + 255) / 256, 256, 0, stream>>>(lb_feat, Qb, 131072 / 4);
  f2bf_kernel<<<(917504 / 4 + 255) / 256, 256, 0, stream>>>(anchor, Qb + (size_t)N_LB * DD, 917504 / 4);

  classnum_kernel<<<(NTOT + 255) / 256, 256, 0, stream>>>(lulb1, lulb2, y_lb, out + O_CN);
  attn_mfma<<<NTOT / 32, 512, 0, stream>>>(Qb, lb_oh, lulb1, out);
}

// Round 3
// 82.684 us; speedup vs baseline: 11.4640x; 1.5648x over previous
//
#include <hip/hip_runtime.h>
#include <math.h>

#define N_LB  1024
#define N_ULB 7168
#define NTOT  8192
#define DD    128
#define CC    10

// float offsets into d_out
#define O_ANCHOR 0
#define O_POS    917504
#define O_LBF    1835008
#define O_LBOH   1966080
#define O_LLB    1976320
#define O_LULB1  1986560
#define O_LULB2  2058240
#define O_CN     2129920

typedef short bf16x8 __attribute__((ext_vector_type(8)));
typedef float f32x16 __attribute__((ext_vector_type(16)));

__device__ __forceinline__ ushort f2bf(float f) {
  union { float f; unsigned u; } a; a.f = f;
  unsigned r = a.u + 0x7FFFu + ((a.u >> 16) & 1u);   // RNE
  return (ushort)(r >> 16);
}
__device__ __forceinline__ float bf2f(ushort u) {
  union { unsigned u; float f; } a; a.u = ((unsigned)u) << 16; return a.f;
}

// -------- prep: all passthrough copies + bf16 staging + class_num -----------
// blocks [0,2000): float4 copies (+ bf16 convert of lb_feat/anchor into ws)
// blocks [2000,2032): class_num histogram (cn pre-zeroed by memset on stream)
__global__ __launch_bounds__(256) void prep_kernel(
    const float* __restrict__ anchor, const float* __restrict__ positive,
    const float* __restrict__ lb_feat, const float* __restrict__ lb_oh,
    const float* __restrict__ lulb1, const float* __restrict__ lulb2,
    const int* __restrict__ y_lb, float* __restrict__ out, ushort* __restrict__ Qb)
{
  const int blk = blockIdx.x;
  if (blk < 2000) {
    int t = blk * 256 + threadIdx.x;
    if (t < 229376) {                       // anchor: copy + bf16 -> Qb[1024*128..]
      float4 v = ((const float4*)anchor)[t];
      ((float4*)(out + O_ANCHOR))[t] = v;
      ushort4 u; u.x = f2bf(v.x); u.y = f2bf(v.y); u.z = f2bf(v.z); u.w = f2bf(v.w);
      ((ushort4*)Qb)[32768 + t] = u;
    } else if (t < 458752) {                // positive: copy
      int t2 = t - 229376;
      ((float4*)(out + O_POS))[t2] = ((const float4*)positive)[t2];
    } else if (t < 491520) {                // lb_feat: copy + bf16 -> Qb[0..]
      int t2 = t - 458752;
      float4 v = ((const float4*)lb_feat)[t2];
      ((float4*)(out + O_LBF))[t2] = v;
      ushort4 u; u.x = f2bf(v.x); u.y = f2bf(v.y); u.z = f2bf(v.z); u.w = f2bf(v.w);
      ((ushort4*)Qb)[t2] = u;
    } else if (t < 494080) {                // lb_one_hot: copy
      int t2 = t - 491520;
      ((float4*)(out + O_LBOH))[t2] = ((const float4*)lb_oh)[t2];
    } else {                                // lulb2: copy
      int t2 = t - 494080;
      ((float4*)(out + O_LULB2))[t2] = ((const float4*)lulb2)[t2];
    }
  } else {
    int t = (blk - 2000) * 256 + threadIdx.x;   // 0..8191
    float* cn = out + O_CN;
    if (t < N_ULB) {
      float a[CC], b[CC];
      #pragma unroll
      for (int c = 0; c < CC; ++c) { a[c] = lulb1[t * CC + c]; b[c] = lulb2[t * CC + c]; }
      float m1 = -INFINITY, m2 = -INFINITY;
      #pragma unroll
      for (int c = 0; c < CC; ++c) { m1 = fmaxf(m1, 2.f * a[c]); m2 = fmaxf(m2, 2.f * b[c]); }
      float Z1 = 0.f, Z2 = 0.f;
      #pragma unroll
      for (int c = 0; c < CC; ++c) { Z1 += expf(2.f * a[c] - m1); Z2 += expf(2.f * b[c] - m2); }
      bool gt = (1.0f / Z1) >= (1.0f / Z2);
      float g[CC];
      #pragma unroll
      for (int c = 0; c < CC; ++c) g[c] = gt ? a[c] : b[c];
      float mg = -INFINITY;
      #pragma unroll
      for (int c = 0; c < CC; ++c) mg = fmaxf(mg, g[c]);
      float p[CC]; float Zg = 0.f;
      #pragma unroll
      for (int c = 0; c < CC; ++c) { p[c] = expf(g[c] - mg); Zg += p[c]; }
      float best = ((p[0] / Zg) >= 0.95f) ? g[0] : 0.0f;
      int bi = 0;
      #pragma unroll
      for (int c = 1; c < CC; ++c) {
        float v = ((p[c] / Zg) >= 0.95f) ? g[c] : 0.0f;
        if (v > best) { best = v; bi = c; }
      }
      if (best != 0.0f) atomicAdd(&cn[bi], 1.0f);
    } else if (t < NTOT) {
      atomicAdd(&cn[y_lb[t - N_ULB]], 1.0f);
    }
  }
}

// -------- attention: MFMA QQ^T, diag-reference softmax, tile-skip -----------
// 256 blocks x 8 waves; block owns 32 rows (A-frags in regs for whole kernel).
// acc init = -||q_row||^2 (C operand of first MFMA) => c_out = dot - ref.
// A tile where all c_out < -2.0 (score < -20) contributes nothing: skip.
__global__ __launch_bounds__(512) void attn_mfma(
    const ushort* __restrict__ Qb, const float* __restrict__ lb_one_hot,
    const float* __restrict__ lulb1, float* __restrict__ out)
{
  __shared__ float lz[8][32];
  __shared__ float lv[8][32];

  const int tid = threadIdx.x;
  const int w  = tid >> 6;
  const int l  = tid & 63;
  const int lr = l & 31;   // A-row / B-col within tile
  const int kh = l >> 5;   // k-half select
  const int blk = blockIdx.x;

  // A fragments: rows blk*32 + lr, k = e*16 + kh*8 + [0..7]
  bf16x8 a[8];
  {
    const ushort* ap = Qb + (size_t)(blk * 32 + lr) * DD + kh * 8;
    #pragma unroll
    for (int e = 0; e < 8; ++e) a[e] = *(const bf16x8*)(ap + e * 16);
  }

  // per-row reference: ||q_row||^2 (dot units)
  float nrm = 0.f;
  #pragma unroll
  for (int e = 0; e < 8; ++e) {
    #pragma unroll
    for (int k = 0; k < 8; ++k) { float q = bf2f((ushort)a[e][k]); nrm = fmaf(q, q, nrm); }
  }
  nrm += __shfl_xor(nrm, 32);   // both k-halves -> full norm of row lr

  // negated reference per C/D slot (row = (e&3)+8*(e>>2)+4*kh)
  f32x16 ncv;
  #pragma unroll
  for (int e = 0; e < 16; ++e) ncv[e] = -__shfl(nrm, (e & 3) + 8 * (e >> 2) + 4 * kh);

  float Z[16], vm[16];
  #pragma unroll
  for (int e = 0; e < 16; ++e) { Z[e] = 0.0f; vm[e] = 0.0f; }

#define LOADB(B, tt) do {                                                      \
    const ushort* _p = Qb + (size_t)((((w) + (tt) * 8) * 32) + lr) * DD + kh * 8; \
    _Pragma("unroll")                                                          \
    for (int e = 0; e < 8; ++e) B[e] = *(const bf16x8*)(_p + e * 16);          \
  } while (0)

#define PROC(B, tt) do {                                                       \
    f32x16 c = __builtin_amdgcn_mfma_f32_32x32x16_bf16(a[0], B[0], ncv, 0, 0, 0); \
    _Pragma("unroll")                                                          \
    for (int e = 1; e < 8; ++e)                                                \
      c = __builtin_amdgcn_mfma_f32_32x32x16_bf16(a[e], B[e], c, 0, 0, 0);     \
    float d0 = fmaxf(fmaxf(fmaxf(c[0], c[1]), fmaxf(c[2], c[3])),              \
                     fmaxf(fmaxf(c[4], c[5]), fmaxf(c[6], c[7])));             \
    float d1 = fmaxf(fmaxf(fmaxf(c[8], c[9]), fmaxf(c[10], c[11])),            \
                     fmaxf(fmaxf(c[12], c[13]), fmaxf(c[14], c[15])));         \
    if (__any(fmaxf(d0, d1) > -2.0f)) {                                        \
      const int jj = (((w) + (tt) * 8) * 32) + lr;                             \
      _Pragma("unroll")                                                        \
      for (int e = 0; e < 16; ++e) {                                           \
        float ex = __expf(c[e] * 10.0f);                                       \
        Z[e] += ex;                                                            \
        vm[e] = fmaxf(vm[e], __int_as_float((__float_as_int(ex) & 0xFFFFE000) | jj)); \
      }                                                                        \
    }                                                                          \
  } while (0)

  bf16x8 bA[8], bB[8];
  LOADB(bA, 0);
  for (int t = 0; t < 32; t += 2) {
    LOADB(bB, (t + 1) & 31);      // prefetch
    PROC(bA, t);
    LOADB(bA, (t + 2) & 31);      // prefetch (wraps harmlessly at t=30)
    PROC(bB, t + 1);
  }
#undef LOADB
#undef PROC

  // reduce across the 32 cols (lanes within each half)
  #pragma unroll
  for (int off = 1; off <= 16; off <<= 1) {
    #pragma unroll
    for (int e = 0; e < 16; ++e) {
      Z[e]  += __shfl_xor(Z[e], off);
      vm[e]  = fmaxf(vm[e], __shfl_xor(vm[e], off));
    }
  }

  if (lr == 0) {
    #pragma unroll
    for (int e = 0; e < 16; ++e) {
      int r = (e & 3) + 8 * (e >> 2) + 4 * kh;
      lz[w][r] = Z[e]; lv[w][r] = vm[e];
    }
  }
  __syncthreads();

  if (tid < 32) {
    float Zf = 0.f, vf = 0.f;
    #pragma unroll
    for (int wv = 0; wv < 8; ++wv) { Zf += lz[wv][tid]; vf = fmaxf(vf, lv[wv][tid]); }
    unsigned bits = __float_as_uint(vf);
    float exm = __uint_as_float(bits & 0xFFFFE000u);
    int   jf  = (int)(bits & 8191u);
    int gi = blk * 32 + tid;
    float av = exm / Zf;
    float* orow = (gi < N_LB) ? (out + O_LLB + (size_t)gi * CC)
                              : (out + O_LULB1 + (size_t)(gi - N_LB) * CC);
    if (av >= 0.6f) {
      if (jf < N_LB) {
        #pragma unroll
        for (int c = 0; c < CC; ++c) orow[c] = av * lb_one_hot[jf * CC + c];
      } else {
        const float* lg = lulb1 + (size_t)(jf - N_LB) * CC;
        float mx = lg[0];
        #pragma unroll
        for (int c = 1; c < CC; ++c) mx = fmaxf(mx, lg[c]);
        float e[CC]; float sum = 0.f;
        #pragma unroll
        for (int c = 0; c < CC; ++c) { e[c] = expf(lg[c] - mx); sum += e[c]; }
        #pragma unroll
        for (int c = 0; c < CC; ++c) orow[c] = av * (e[c] / sum);
      }
    } else {
      #pragma unroll
      for (int c = 0; c < CC; ++c) orow[c] = 0.0f;
    }
  }
}

extern "C" void kernel_launch(void* const* d_in, const int* in_sizes, int n_in,
                              void* d_out, int out_size, void* d_ws, size_t ws_size,
                              hipStream_t stream) {
  (void)in_sizes; (void)n_in; (void)ws_size; (void)out_size;
  const float* anchor   = (const float*)d_in[0];
  const float* positive = (const float*)d_in[1];
  const float* lb_feat  = (const float*)d_in[2];
  const float* lb_oh    = (const float*)d_in[3];
  const float* lulb1    = (const float*)d_in[5];
  const float* lulb2    = (const float*)d_in[6];
  const int*   y_lb     = (const int*)d_in[7];
  float* out = (float*)d_out;
  ushort* Qb = (ushort*)d_ws;   // 8192 x 128 bf16 = 2 MB

  hipMemsetAsync(out + O_CN, 0, CC * sizeof(float), stream);
  prep_kernel<<<2032, 256, 0, stream>>>(anchor, positive, lb_feat, lb_oh,
                                        lulb1, lulb2, y_lb, out, Qb);
  attn_mfma<<<NTOT / 32, 512, 0, stream>>>(Qb, lb_oh, lulb1, out);
}

// Round 4
// 44.606 us; speedup vs baseline: 21.2501x; 1.8536x over previous
//
#include <hip/hip_runtime.h>
#include <math.h>

#define N_LB  1024
#define N_ULB 7168
#define NTOT  8192
#define DD    128
#define CC    10

// float offsets into d_out
#define O_ANCHOR 0
#define O_POS    917504
#define O_LBF    1835008
#define O_LBOH   1966080
#define O_LLB    1976320
#define O_LULB1  1986560
#define O_LULB2  2058240
#define O_CN     2129920

typedef short bf16x8 __attribute__((ext_vector_type(8)));
typedef float f32x16 __attribute__((ext_vector_type(16)));

__device__ __forceinline__ ushort f2bf(float f) {
  union { float f; unsigned u; } a; a.f = f;
  unsigned r = a.u + 0x7FFFu + ((a.u >> 16) & 1u);   // RNE
  return (ushort)(r >> 16);
}
__device__ __forceinline__ float bf2f(ushort u) {
  union { unsigned u; float f; } a; a.u = ((unsigned)u) << 16; return a.f;
}

// Fragment-major Q layout: 16B chunk (8 bf16) for global row r, col-chunk kc
// (cols kc*8..kc*8+7) lives at ushort offset:
//   tile=(r>>5), e=kc>>1, lane=(r&31)+32*(kc&1):  tile*4096 + e*512 + lane*8
// This makes every MFMA A/B fragment load lane-contiguous (1KB/instruction).
__device__ __forceinline__ size_t qfrag_off(int r, int kc) {
  return (size_t)(r >> 5) * 4096 + (size_t)(kc >> 1) * 512
       + (size_t)((r & 31) + 32 * (kc & 1)) * 8;
}

// -------- prep: passthrough copies + fragment-major bf16 staging + class_num
__global__ __launch_bounds__(256) void prep_kernel(
    const float* __restrict__ anchor, const float* __restrict__ positive,
    const float* __restrict__ lb_feat, const float* __restrict__ lb_oh,
    const float* __restrict__ lulb1, const float* __restrict__ lulb2,
    const int* __restrict__ y_lb, float* __restrict__ out, ushort* __restrict__ Qf)
{
  const int blk = blockIdx.x;
  if (blk < 2000) {
    int t = blk * 256 + threadIdx.x;
    if (t < 229376) {                       // anchor: copy + bf16 frag-major
      float4 v = ((const float4*)anchor)[t];
      ((float4*)(out + O_ANCHOR))[t] = v;
      ushort4 u; u.x = f2bf(v.x); u.y = f2bf(v.y); u.z = f2bf(v.z); u.w = f2bf(v.w);
      int r = N_LB + (t >> 5), c4 = t & 31;
      *(ushort4*)(Qf + qfrag_off(r, c4 >> 1) + (c4 & 1) * 4) = u;
    } else if (t < 458752) {                // positive: copy
      int t2 = t - 229376;
      ((float4*)(out + O_POS))[t2] = ((const float4*)positive)[t2];
    } else if (t < 491520) {                // lb_feat: copy + bf16 frag-major
      int t2 = t - 458752;
      float4 v = ((const float4*)lb_feat)[t2];
      ((float4*)(out + O_LBF))[t2] = v;
      ushort4 u; u.x = f2bf(v.x); u.y = f2bf(v.y); u.z = f2bf(v.z); u.w = f2bf(v.w);
      int r = t2 >> 5, c4 = t2 & 31;
      *(ushort4*)(Qf + qfrag_off(r, c4 >> 1) + (c4 & 1) * 4) = u;
    } else if (t < 494080) {                // lb_one_hot: copy
      int t2 = t - 491520;
      ((float4*)(out + O_LBOH))[t2] = ((const float4*)lb_oh)[t2];
    } else {                                // lulb2: copy
      int t2 = t - 494080;
      ((float4*)(out + O_LULB2))[t2] = ((const float4*)lulb2)[t2];
    }
  } else {
    int t = (blk - 2000) * 256 + threadIdx.x;   // 0..8191
    float* cn = out + O_CN;
    if (t < N_ULB) {
      float a[CC], b[CC];
      #pragma unroll
      for (int c = 0; c < CC; ++c) { a[c] = lulb1[t * CC + c]; b[c] = lulb2[t * CC + c]; }
      float m1 = -INFINITY, m2 = -INFINITY;
      #pragma unroll
      for (int c = 0; c < CC; ++c) { m1 = fmaxf(m1, 2.f * a[c]); m2 = fmaxf(m2, 2.f * b[c]); }
      float Z1 = 0.f, Z2 = 0.f;
      #pragma unroll
      for (int c = 0; c < CC; ++c) { Z1 += expf(2.f * a[c] - m1); Z2 += expf(2.f * b[c] - m2); }
      bool gt = (1.0f / Z1) >= (1.0f / Z2);
      float g[CC];
      #pragma unroll
      for (int c = 0; c < CC; ++c) g[c] = gt ? a[c] : b[c];
      float mg = -INFINITY;
      #pragma unroll
      for (int c = 0; c < CC; ++c) mg = fmaxf(mg, g[c]);
      float p[CC]; float Zg = 0.f;
      #pragma unroll
      for (int c = 0; c < CC; ++c) { p[c] = expf(g[c] - mg); Zg += p[c]; }
      float best = ((p[0] / Zg) >= 0.95f) ? g[0] : 0.0f;
      int bi = 0;
      #pragma unroll
      for (int c = 1; c < CC; ++c) {
        float v = ((p[c] / Zg) >= 0.95f) ? g[c] : 0.0f;
        if (v > best) { best = v; bi = c; }
      }
      if (best != 0.0f) atomicAdd(&cn[bi], 1.0f);
    } else if (t < NTOT) {
      atomicAdd(&cn[y_lb[t - N_ULB]], 1.0f);
    }
  }
}

// -------- attn_main: 256 blocks = 128 row-groups x 2 j-halves ---------------
// Block owns 64 A-rows (2 MFMA tiles, frags in regs), scans 4096 j's.
// Per B-tile: coalesced frag loads, 16 MFMA, max-tree + skip, rare exp path.
// Writes per-row partials (Z, packed-max) to ws; reference = ||q_row||^2.
__global__ __launch_bounds__(512, 2) void attn_main(
    const ushort* __restrict__ Qf, float* __restrict__ part)
{
  __shared__ float lz[8][64];
  __shared__ float lv[8][64];

  const int tid = threadIdx.x;
  const int w  = tid >> 6;
  const int l  = tid & 63;
  const int lr = l & 31;
  const int kh = l >> 5;
  const int g  = blockIdx.x >> 1;   // row-group: rows g*64 .. g*64+63
  const int h  = blockIdx.x & 1;    // j-half

  bf16x8 a0[8], a1[8];
  {
    const ushort* p0 = Qf + (size_t)(2 * g)     * 4096 + l * 8;
    const ushort* p1 = Qf + (size_t)(2 * g + 1) * 4096 + l * 8;
    #pragma unroll
    for (int e = 0; e < 8; ++e) {
      a0[e] = *(const bf16x8*)(p0 + e * 512);
      a1[e] = *(const bf16x8*)(p1 + e * 512);
    }
  }

  // per-row references ||q||^2 (lane lr holds row lr / 32+lr after xor-32)
  float n0 = 0.f, n1 = 0.f;
  #pragma unroll
  for (int e = 0; e < 8; ++e) {
    #pragma unroll
    for (int k = 0; k < 8; ++k) {
      float q0 = bf2f((ushort)a0[e][k]); n0 = fmaf(q0, q0, n0);
      float q1 = bf2f((ushort)a1[e][k]); n1 = fmaf(q1, q1, n1);
    }
  }
  n0 += __shfl_xor(n0, 32);
  n1 += __shfl_xor(n1, 32);

  // conservative skip threshold: min reference over the block's 64 rows
  float nm = fminf(n0, n1);
  #pragma unroll
  for (int off = 1; off <= 16; off <<= 1) nm = fminf(nm, __shfl_xor(nm, off));
  const float thr = nm - 2.0f;

  float Z0[16], Z1[16], vm0[16], vm1[16];
  #pragma unroll
  for (int e = 0; e < 16; ++e) { Z0[e] = 0.f; Z1[e] = 0.f; vm0[e] = 0.f; vm1[e] = 0.f; }

#define LOADB(B, tt) do {                                                      \
    const ushort* _p = Qf + (size_t)(h * 128 + w + (tt) * 8) * 4096 + l * 8;   \
    _Pragma("unroll")                                                          \
    for (int e = 0; e < 8; ++e) B[e] = *(const bf16x8*)(_p + e * 512);         \
  } while (0)

#define PROC(B, tt) do {                                                       \
    f32x16 zz;                                                                 \
    _Pragma("unroll")                                                          \
    for (int e = 0; e < 16; ++e) zz[e] = 0.0f;                                 \
    f32x16 c0 = zz, c1 = zz;                                                   \
    _Pragma("unroll")                                                          \
    for (int e = 0; e < 8; ++e) {                                              \
      c0 = __builtin_amdgcn_mfma_f32_32x32x16_bf16(a0[e], B[e], c0, 0, 0, 0);  \
      c1 = __builtin_amdgcn_mfma_f32_32x32x16_bf16(a1[e], B[e], c1, 0, 0, 0);  \
    }                                                                          \
    float dm = -INFINITY;                                                      \
    _Pragma("unroll")                                                          \
    for (int e = 0; e < 16; ++e) dm = fmaxf(dm, fmaxf(c0[e], c1[e]));          \
    if (__any(dm > thr)) {                                                     \
      const int jj = (h * 128 + w + (tt) * 8) * 32 + lr;                       \
      _Pragma("unroll")                                                        \
      for (int e = 0; e < 16; ++e) {                                           \
        int rr = (e & 3) + 8 * (e >> 2) + 4 * kh;                              \
        float r0 = __shfl(n0, rr), r1 = __shfl(n1, rr);                        \
        float e0 = __expf((c0[e] - r0) * 10.f);                                \
        float e1 = __expf((c1[e] - r1) * 10.f);                                \
        Z0[e] += e0; Z1[e] += e1;                                              \
        vm0[e] = fmaxf(vm0[e], __int_as_float((__float_as_int(e0) & 0xFFFFE000) | jj)); \
        vm1[e] = fmaxf(vm1[e], __int_as_float((__float_as_int(e1) & 0xFFFFE000) | jj)); \
      }                                                                        \
    }                                                                          \
  } while (0)

  bf16x8 bA[8], bB[8];
  LOADB(bA, 0);
  for (int t = 0; t < 16; t += 2) {
    LOADB(bB, t + 1);
    PROC(bA, t);
    LOADB(bA, (t + 2) & 15);
    PROC(bB, t + 1);
  }
#undef LOADB
#undef PROC

  // reduce across 32 cols (lanes within each half)
  #pragma unroll
  for (int off = 1; off <= 16; off <<= 1) {
    #pragma unroll
    for (int e = 0; e < 16; ++e) {
      Z0[e] += __shfl_xor(Z0[e], off);
      Z1[e] += __shfl_xor(Z1[e], off);
      vm0[e] = fmaxf(vm0[e], __shfl_xor(vm0[e], off));
      vm1[e] = fmaxf(vm1[e], __shfl_xor(vm1[e], off));
    }
  }

  if (lr == 0) {
    #pragma unroll
    for (int e = 0; e < 16; ++e) {
      int rr = (e & 3) + 8 * (e >> 2) + 4 * kh;
      lz[w][rr]      = Z0[e]; lv[w][rr]      = vm0[e];
      lz[w][32 + rr] = Z1[e]; lv[w][32 + rr] = vm1[e];
    }
  }
  __syncthreads();

  if (tid < 64) {
    float Zf = 0.f, vf = 0.f;
    #pragma unroll
    for (int wv = 0; wv < 8; ++wv) { Zf += lz[wv][tid]; vf = fmaxf(vf, lv[wv][tid]); }
    part[(size_t)(blockIdx.x * 64 + tid) * 2]     = Zf;
    part[(size_t)(blockIdx.x * 64 + tid) * 2 + 1] = vf;
  }
}

// -------- attn_final: merge j-half partials + epilogue ----------------------
__global__ __launch_bounds__(256) void attn_final(
    const float* __restrict__ part, const float* __restrict__ lb_one_hot,
    const float* __restrict__ lulb1, float* __restrict__ out)
{
  int i = blockIdx.x * 256 + threadIdx.x;   // global row 0..8191
  if (i >= NTOT) return;
  int g = i >> 6, loc = i & 63;
  size_t i0 = (size_t)((g * 2)     * 64 + loc) * 2;
  size_t i1 = (size_t)((g * 2 + 1) * 64 + loc) * 2;
  float Zf = part[i0] + part[i1];
  float vf = fmaxf(part[i0 + 1], part[i1 + 1]);
  unsigned bits = __float_as_uint(vf);
  float exm = __uint_as_float(bits & 0xFFFFE000u);
  int   jf  = (int)(bits & 8191u);
  float av = exm / Zf;
  float* orow = (i < N_LB) ? (out + O_LLB + (size_t)i * CC)
                           : (out + O_LULB1 + (size_t)(i - N_LB) * CC);
  if (av >= 0.6f) {
    if (jf < N_LB) {
      #pragma unroll
      for (int c = 0; c < CC; ++c) orow[c] = av * lb_one_hot[jf * CC + c];
    } else {
      const float* lg = lulb1 + (size_t)(jf - N_LB) * CC;
      float mx = lg[0];
      #pragma unroll
      for (int c = 1; c < CC; ++c) mx = fmaxf(mx, lg[c]);
      float e[CC]; float sum = 0.f;
      #pragma unroll
      for (int c = 0; c < CC; ++c) { e[c] = expf(lg[c] - mx); sum += e[c]; }
      #pragma unroll
      for (int c = 0; c < CC; ++c) orow[c] = av * (e[c] / sum);
    }
  } else {
    #pragma unroll
    for (int c = 0; c < CC; ++c) orow[c] = 0.0f;
  }
}

extern "C" void kernel_launch(void* const* d_in, const int* in_sizes, int n_in,
                              void* d_out, int out_size, void* d_ws, size_t ws_size,
                              hipStream_t stream) {
  (void)in_sizes; (void)n_in; (void)ws_size; (void)out_size;
  const float* anchor   = (const float*)d_in[0];
  const float* positive = (const float*)d_in[1];
  const float* lb_feat  = (const float*)d_in[2];
  const float* lb_oh    = (const float*)d_in[3];
  const float* lulb1    = (const float*)d_in[5];
  const float* lulb2    = (const float*)d_in[6];
  const int*   y_lb     = (const int*)d_in[7];
  float* out = (float*)d_out;
  ushort* Qf  = (ushort*)d_ws;                          // 2 MB fragment-major Q
  float* part = (float*)((char*)d_ws + (2u << 20));     // 128 KB partials

  hipMemsetAsync(out + O_CN, 0, CC * sizeof(float), stream);
  prep_kernel<<<2032, 256, 0, stream>>>(anchor, positive, lb_feat, lb_oh,
                                        lulb1, lulb2, y_lb, out, Qf);
  attn_main<<<256, 512, 0, stream>>>(Qf, part);
  attn_final<<<32, 256, 0, stream>>>(part, lb_oh, lulb1, out);
}